// Round 5
// baseline (352.802 us; speedup 1.0000x reference)
//
#include <hip/hip_runtime.h>
#include <hip/hip_bf16.h>
#include <math.h>

// HGT layer forward, MI355X.
//  - fold rel_att/rel_msg einsums into projection weights; KV interleave baked into the
//    fused weight COLUMN ORDER (cols independent -> permutation is numerically identity)
//  - rel_pri * (1/sqrt(DK)) * log2(e) folded into the fused K columns (and k-bias) ->
//    aggregate applies exp2 directly to the dot product, no per-edge scale mul
//  - Q/KV intermediate planes stored as F16: score dot = v_dot2_f32_f16, message accum
//    fmaf (v_fma_mix) -> no unpack ops in the aggregate inner loop
//  - scatter OVERLAPPED with projection GEMM (merged grid; scatter blocks dispatch first):
//    R0/R3 showed the bucket scatter is a scattered-transaction wall (~85-90us; ILP x8 and
//    parallelism both no-ops) -> co-runs with the MFMA-bound GEMM
//  - workspace zeroing folded into prep's grid (one fewer dispatch + gap)
//  - aggregate v4: first 8-edge batch + ALL address calc upfront (keeps R3's short
//    dependency chain); second batch's LOADS gated behind uniform cnt>8 (45% of waves)
//    -> ~30% fewer scattered line-transactions vs R3's unconditional issue
//  - epi: fp32 LDS stage -> coalesced float4 Hres blend + store (aggR stays bf16)
//  - fixed-capacity buckets (CAP=40, deg~Poisson(8))

#define NN 50000
#define EE 400000
#define CAP 40

typedef __bf16 bf16x8 __attribute__((ext_vector_type(8)));
typedef float floatx4 __attribute__((ext_vector_type(4)));
typedef _Float16 h2 __attribute__((ext_vector_type(2)));

#if __has_builtin(__builtin_amdgcn_exp2f)
#define EXP2F(x) __builtin_amdgcn_exp2f(x)
#else
#define EXP2F(x) exp2f(x)
#endif

__device__ __forceinline__ h2 u_to_h2(unsigned int u) {
    union { unsigned int u; h2 h; } x; x.u = u; return x.h;
}

__device__ __forceinline__ float dot2f(h2 a, h2 b, float c) {
#if __has_builtin(__builtin_amdgcn_fdot2)
    return __builtin_amdgcn_fdot2(a, b, c, false);
#else
    return fmaf((float)a.x, (float)b.x, fmaf((float)a.y, (float)b.y, c));
#endif
}

// xor-butterfly add stages; same pairwise tree as __shfl_xor version -> bit-identical.
__device__ __forceinline__ float xor1_add(float x) {
#if __has_builtin(__builtin_amdgcn_mov_dpp)
    int y = __builtin_amdgcn_mov_dpp(__float_as_int(x), 0xB1, 0xf, 0xf, true); // quad_perm [1,0,3,2]
    return x + __int_as_float(y);
#else
    return x + __shfl_xor(x, 1);
#endif
}
__device__ __forceinline__ float xor2_add(float x) {
#if __has_builtin(__builtin_amdgcn_mov_dpp)
    int y = __builtin_amdgcn_mov_dpp(__float_as_int(x), 0x4E, 0xf, 0xf, true); // quad_perm [2,3,0,1]
    return x + __int_as_float(y);
#else
    return x + __shfl_xor(x, 2);
#endif
}
__device__ __forceinline__ float xor4_add(float x) {
#if __has_builtin(__builtin_amdgcn_ds_swizzle)
    int y = __builtin_amdgcn_ds_swizzle(__float_as_int(x), 0x101F); // xor lane^4
    return x + __int_as_float(y);
#else
    return x + __shfl_xor(x, 4);
#endif
}

// ---------------------------------------------------------------- prep: fuse weights + zero ws
// Wcat0T [384col][128k]: q0 | rel0-KV(256, interleaved col order)
// Wcat1T [640col][128k]: q1 | rel1-KV(256) | rel2-KV(256)
// KV col gc in [0,256): group=gc>>3, slot=(gc>>2)&1 (0=k,1=v), dim=(gc>>3)*4+(gc&3)
// K columns (and k-bias) pre-scaled by rel_pri[r][h]/sqrt(DK)*log2e.
// WaT [2][128col][128k]
// Blocks [0,FUSEB): fuse. Blocks [FUSEB, FUSEB+ZB): zero cursor+sorted (64B/thread).
#define FUSEB 640
__global__ __launch_bounds__(256) void prep(
    const float* __restrict__ Wk, const float* __restrict__ bk,
    const float* __restrict__ Wq, const float* __restrict__ bq,
    const float* __restrict__ Wv, const float* __restrict__ bv,
    const float* __restrict__ rel_att, const float* __restrict__ rel_msg,
    const float* __restrict__ rel_pri, const float* __restrict__ Wa,
    __hip_bfloat16* __restrict__ Wcat0T, __hip_bfloat16* __restrict__ Wcat1T,
    __hip_bfloat16* __restrict__ WaT,
    float* __restrict__ bcat0, float* __restrict__ bcat1,
    int* __restrict__ zero_base, int zero_n4)
{
    if (blockIdx.x >= FUSEB) {
        // ---- zero region: each thread writes 4 consecutive int4 (64 B)
        int zb = blockIdx.x - FUSEB;
        size_t base = ((size_t)zb * 256 + threadIdx.x) * 4;
        int4* p = (int4*)zero_base;
        int4 z = make_int4(0, 0, 0, 0);
        #pragma unroll
        for (int u = 0; u < 4; ++u) {
            size_t idx = base + u;
            if (idx < (size_t)zero_n4) p[idx] = z;
        }
        return;
    }
    int idx = blockIdx.x * 256 + threadIdx.x;
    const int R1 = 128 * 384, R2 = 128 * 640, R3 = 2 * 128 * 128;
    if (idx >= R1 + R2 + R3) return;
    if (idx >= R1 + R2) {               // WaT transpose region
        int t = idx - R1 - R2;
        int tt = t >> 14, rem = t & 16383;
        int k = rem >> 7, col = rem & 127;
        WaT[tt * 16384 + col * 128 + k] = __float2bfloat16(Wa[tt * 16384 + k * 128 + col]);
        return;
    }
    int typ, i, col;
    __hip_bfloat16* Wout; float* bout;
    if (idx < R1) { typ = 0; i = idx / 384; col = idx % 384; Wout = Wcat0T; bout = bcat0; }
    else { idx -= R1; typ = 1; i = idx / 640; col = idx % 640; Wout = Wcat1T; bout = bcat1; }
    float w, b;
    if (col < 128) {
        w = Wq[(typ * 128 + i) * 128 + col];
        b = bq[typ * 128 + col];
    } else {
        int kvcol = col - 128;
        int r = (typ == 0) ? 0 : (1 + (kvcol >> 8));
        int gc = kvcol & 255;
        int isV = (gc >> 2) & 1;
        int c = (gc >> 3) * 4 + (gc & 3);   // head-dim within 128
        int s = typ;
        const float* Wsrc = isV ? Wv : Wk;
        const float* bsrc = isV ? bv : bk;
        const float* rel  = isV ? rel_msg : rel_att;
        int h = c >> 5, j = c & 31;
        float acc = 0.f, bacc = 0.f;
        #pragma unroll
        for (int cc = 0; cc < 32; ++cc) {
            float rr = rel[((r * 4 + h) * 32 + cc) * 32 + j];
            acc  += Wsrc[(s * 128 + i) * 128 + h * 32 + cc] * rr;
            bacc += bsrc[s * 128 + h * 32 + cc] * rr;
        }
        if (!isV) {
            float sc = rel_pri[r * 4 + h] * (0.17677669529663687f * 1.4426950408889634f);
            acc *= sc; bacc *= sc;
        }
        w = acc; b = bacc;
    }
    Wout[col * 128 + i] = __float2bfloat16(w);   // transposed [col][k]
    if (i == 0) bout[col] = b;
}

// ---------------------------------------------------------------- projection GEMM + scatter
// Blocks x < SCATX: bucket scatter (8 edges/thread, 8 independent atomicAdd-with-return
// in flight; scattered-transaction-bound, overlaps the GEMM blocks behind it).
// Blocks x >= SCATX: GEMM. Stage A once; loop col-tiles. ct=0 -> Q[N][128]; else
// KV_rel[N][256] slice. C-write: acc -> Bs (dead after MFMA) -> coalesced dwordx4 stores.
// Output planes are F16 bits (consumed by aggregate via dot2/fma_mix).
#define SCATB 196      // scatter blocks per relation (196*2048 >= EE)
#define SCATX 294      // scatter blocks per y-slice (2*294 = 3*196)
__global__ __launch_bounds__(256) void proj_both(
    const float* __restrict__ h0, const float* __restrict__ h1,
    const __hip_bfloat16* __restrict__ W0T, const __hip_bfloat16* __restrict__ W1T,
    const float* __restrict__ b0, const float* __restrict__ b1,
    ushort* __restrict__ Q0, ushort* __restrict__ Q1,
    ushort* __restrict__ KV0, ushort* __restrict__ KV1,
    ushort* __restrict__ KV2,
    const int* __restrict__ s0, const int* __restrict__ d0,
    const int* __restrict__ s1, const int* __restrict__ d1,
    const int* __restrict__ s2, const int* __restrict__ d2,
    int* __restrict__ cursor, int* __restrict__ sorted_src)
{
    __shared__ __align__(16) __hip_bfloat16 As[128][136];
    __shared__ __align__(16) ushort Bs[128][136];
    const int tid = threadIdx.x;

    if (blockIdx.x < SCATX) {
        // ---- scatter region: dispatched first, overlaps GEMM
        int sb = blockIdx.y * SCATX + blockIdx.x;   // [0, 588)
        int r = sb / SCATB;
        int blk = sb - r * SCATB;
        const int* S = (r == 0) ? s0 : (r == 1) ? s1 : s2;
        const int* D = (r == 0) ? d0 : (r == 1) ? d1 : d2;
        int e0 = blk * 2048 + tid * 8;
        if (e0 + 8 <= EE) {
            int sv[8], dv[8], pos[8];
            *(int4*)&sv[0] = *(const int4*)(S + e0);
            *(int4*)&sv[4] = *(const int4*)(S + e0 + 4);
            *(int4*)&dv[0] = *(const int4*)(D + e0);
            *(int4*)&dv[4] = *(const int4*)(D + e0 + 4);
            #pragma unroll
            for (int j = 0; j < 8; ++j)
                pos[j] = atomicAdd(&cursor[r * NN + dv[j]], 1);
            #pragma unroll
            for (int j = 0; j < 8; ++j)
                if (pos[j] < CAP)
                    sorted_src[(size_t)(r * NN + dv[j]) * CAP + pos[j]] = sv[j];
        } else {
            // tail block only: guarded scalar path
            for (int j = 0; j < 8; ++j) {
                int e = e0 + j;
                if (e >= EE) break;
                int idx = r * NN + D[e];
                int pos = atomicAdd(&cursor[idx], 1);
                if (pos < CAP) sorted_src[(size_t)idx * CAP + pos] = S[e];
            }
        }
        return;
    }

    const int row0 = (blockIdx.x - SCATX) * 128;
    const int typ = blockIdx.y;
    const float* A = typ ? h1 : h0;
    const __hip_bfloat16* WT = typ ? W1T : W0T;
    const float* bias = typ ? b1 : b0;
    const int ntiles = typ ? 5 : 3;

    #pragma unroll
    for (int it = 0; it < 16; ++it) {
        int li = it * 256 + tid;
        int r = li >> 5, k4 = (li & 31) * 4;
        int grow = row0 + r;
        float4 a4 = make_float4(0.f, 0.f, 0.f, 0.f);
        if (grow < NN) a4 = *(const float4*)(A + (size_t)grow * 128 + k4);
        As[r][k4 + 0] = __float2bfloat16(a4.x);
        As[r][k4 + 1] = __float2bfloat16(a4.y);
        As[r][k4 + 2] = __float2bfloat16(a4.z);
        As[r][k4 + 3] = __float2bfloat16(a4.w);
    }

    const int lane = tid & 63;
    const int wv = tid >> 6;
    const int wr = (wv & 1) * 64, wc = (wv >> 1) * 64;
    const int lr = lane & 15, kq = lane >> 4;

    for (int ct = 0; ct < ntiles; ++ct) {
        __syncthreads();
        #pragma unroll
        for (int it = 0; it < 8; ++it) {
            int li = it * 256 + tid;
            int c = li >> 4, k8 = (li & 15) * 8;
            *(uint4*)&Bs[c][k8] = *(const uint4*)(WT + (size_t)(ct * 128 + c) * 128 + k8);
        }
        __syncthreads();

        floatx4 acc[4][4];
        #pragma unroll
        for (int i = 0; i < 4; ++i)
            #pragma unroll
            for (int j = 0; j < 4; ++j)
                acc[i][j] = (floatx4){0.f, 0.f, 0.f, 0.f};

        #pragma unroll
        for (int kc = 0; kc < 128; kc += 32) {
            bf16x8 a[4], b[4];
            #pragma unroll
            for (int i = 0; i < 4; ++i) a[i] = *(const bf16x8*)&As[wr + i * 16 + lr][kc + kq * 8];
            #pragma unroll
            for (int j = 0; j < 4; ++j) b[j] = *(const bf16x8*)&Bs[wc + j * 16 + lr][kc + kq * 8];
            #pragma unroll
            for (int i = 0; i < 4; ++i)
                #pragma unroll
                for (int j = 0; j < 4; ++j)
                    acc[i][j] = __builtin_amdgcn_mfma_f32_16x16x32_bf16(a[i], b[j], acc[i][j], 0, 0, 0);
        }

        float biasv[4];
        #pragma unroll
        for (int j = 0; j < 4; ++j) biasv[j] = bias[ct * 128 + wc + j * 16 + lr];

        __syncthreads();
        #pragma unroll
        for (int i = 0; i < 4; ++i)
            #pragma unroll
            for (int reg = 0; reg < 4; ++reg) {
                int row = wr + i * 16 + kq * 4 + reg;
                #pragma unroll
                for (int j = 0; j < 4; ++j) {
                    union { _Float16 h; ushort s; } cv;
                    cv.h = (_Float16)(acc[i][j][reg] + biasv[j]);
                    Bs[row][wc + j * 16 + lr] = cv.s;
                }
            }
        __syncthreads();

        ushort* plane; int ld, toff;
        if (ct == 0) { plane = typ ? Q1 : Q0; ld = 128; toff = 0; }
        else {
            int rel = typ ? (1 + ((ct - 1) >> 1)) : 0;
            plane = (rel == 0) ? KV0 : (rel == 1) ? KV1 : KV2;
            ld = 256; toff = ((ct - 1) & 1) * 128;
        }
        #pragma unroll
        for (int it = 0; it < 8; ++it) {
            int li = it * 256 + tid;
            int row = li >> 4, chunk = (li & 15) * 8;
            int grow = row0 + row;
            if (grow < NN)
                *(uint4*)(plane + (size_t)grow * ld + toff + chunk) = *(const uint4*)&Bs[row][chunk];
        }
    }
}

// ---------------------------------------------------------------- epilogue GEMM
__device__ __forceinline__ void epi_body(
    char* smem,
    const __hip_bfloat16* __restrict__ A0, const __hip_bfloat16* __restrict__ A1, float ascale,
    const __hip_bfloat16* __restrict__ BT, const float* __restrict__ bias,
    float* __restrict__ C, const float* __restrict__ skipGate, const float* __restrict__ Hres)
{
    typedef __hip_bfloat16 bfrow[136];
    bfrow* As = (bfrow*)smem;
    bfrow* Bs = (bfrow*)(smem + 128 * 136 * 2);
    typedef float frow[132];
    frow* St = (frow*)smem;                 // overlays As+Bs after MFMA
    const int tid = threadIdx.x;
    const int row0 = blockIdx.x * 128;

    #pragma unroll
    for (int it = 0; it < 8; ++it) {
        int li = it * 256 + tid;
        int c = li >> 4, k8 = (li & 15) * 8;
        *(uint4*)&Bs[c][k8] = *(const uint4*)(BT + (size_t)c * 128 + k8);
    }
    #pragma unroll
    for (int it = 0; it < 8; ++it) {
        int li = it * 256 + tid;
        int r = li >> 4, k8 = (li & 15) * 8;
        int grow = row0 + r;
        __hip_bfloat162 o2[4];
        if (grow < NN) {
            const __hip_bfloat162* pa = (const __hip_bfloat162*)(A0 + (size_t)grow * 128 + k8);
            if (A1) {
                const __hip_bfloat162* pb = (const __hip_bfloat162*)(A1 + (size_t)grow * 128 + k8);
                #pragma unroll
                for (int u = 0; u < 4; ++u) {
                    float2 fa = __bfloat1622float2(pa[u]);
                    float2 fb = __bfloat1622float2(pb[u]);
                    fa.x = (fa.x + fb.x) * ascale;
                    fa.y = (fa.y + fb.y) * ascale;
                    o2[u] = __float22bfloat162_rn(fa);
                }
            } else {
                #pragma unroll
                for (int u = 0; u < 4; ++u) o2[u] = pa[u];
            }
        } else {
            __hip_bfloat162 zz = __float22bfloat162_rn(make_float2(0.f, 0.f));
            #pragma unroll
            for (int u = 0; u < 4; ++u) o2[u] = zz;
        }
        __hip_bfloat162* dst = (__hip_bfloat162*)&As[r][k8];
        #pragma unroll
        for (int u = 0; u < 4; ++u) dst[u] = o2[u];
    }
    __syncthreads();

    const int lane = tid & 63;
    const int wv = tid >> 6;
    const int wr = (wv & 1) * 64, wc = (wv >> 1) * 64;
    const int lr = lane & 15, kq = lane >> 4;

    floatx4 acc[4][4];
    #pragma unroll
    for (int i = 0; i < 4; ++i)
        #pragma unroll
        for (int j = 0; j < 4; ++j)
            acc[i][j] = (floatx4){0.f, 0.f, 0.f, 0.f};

    #pragma unroll
    for (int kc = 0; kc < 128; kc += 32) {
        bf16x8 a[4], b[4];
        #pragma unroll
        for (int i = 0; i < 4; ++i) a[i] = *(const bf16x8*)&As[wr + i * 16 + lr][kc + kq * 8];
        #pragma unroll
        for (int j = 0; j < 4; ++j) b[j] = *(const bf16x8*)&Bs[wc + j * 16 + lr][kc + kq * 8];
        #pragma unroll
        for (int i = 0; i < 4; ++i)
            #pragma unroll
            for (int j = 0; j < 4; ++j)
                acc[i][j] = __builtin_amdgcn_mfma_f32_16x16x32_bf16(a[i], b[j], acc[i][j], 0, 0, 0);
    }

    float sg = *skipGate;
    float alpha = 1.f / (1.f + expf(-sg));
    float beta = 1.f - alpha;
    float biasv[4];
    #pragma unroll
    for (int j = 0; j < 4; ++j) biasv[j] = bias[wc + j * 16 + lr];

    __syncthreads();
    #pragma unroll
    for (int i = 0; i < 4; ++i)
        #pragma unroll
        for (int reg = 0; reg < 4; ++reg) {
            int row = wr + i * 16 + kq * 4 + reg;
            #pragma unroll
            for (int j = 0; j < 4; ++j)
                St[row][wc + j * 16 + lr] = acc[i][j][reg] + biasv[j];
        }
    __syncthreads();

    #pragma unroll
    for (int it = 0; it < 16; ++it) {
        int li = it * 256 + tid;
        int row = li >> 5, chunk = (li & 31) * 4;
        int grow = row0 + row;
        if (grow < NN) {
            float4 v = *(const float4*)&St[row][chunk];
            float4 hr = *(const float4*)(Hres + (size_t)grow * 128 + chunk);
            v.x = v.x * alpha + hr.x * beta;
            v.y = v.y * alpha + hr.y * beta;
            v.z = v.z * alpha + hr.z * beta;
            v.w = v.w * alpha + hr.w * beta;
            *(float4*)(C + (size_t)grow * 128 + chunk) = v;
        }
    }
}

__global__ __launch_bounds__(256) void epi_both(
    const __hip_bfloat16* __restrict__ aggR0, const __hip_bfloat16* __restrict__ aggR1,
    const __hip_bfloat16* __restrict__ aggR2,
    const __hip_bfloat16* __restrict__ WaT, const float* __restrict__ ba,
    float* __restrict__ out, const float* __restrict__ skip,
    const float* __restrict__ h0, const float* __restrict__ h1)
{
    __shared__ __align__(16) char smem[128 * 136 * 2 * 2];
    if (blockIdx.y == 0)
        epi_body(smem, aggR1, nullptr, 1.f, WaT, ba, out, skip, h0);
    else
        epi_body(smem, aggR0, aggR2, 0.5f, WaT + 16384, ba + 128,
                 out + (size_t)NN * 128, skip + 1, h1);
}

// ---------------------------------------------------------------- aggregate
// Grid y = relation; one wave per dst node. hl=lane&31 covers dims 4hl..4hl+3;
// half=lane>>5 is edge parity. sorted zero-filled -> gather addresses depend only
// on elist; masks (cnt) consumed at exp stage only. First 8-edge batch + all
// address calc upfront (short dep chain); second batch LOADS gated by uniform
// cnt>8 (45% of waves) -> ~30% fewer scattered line-transactions. KV/Q planes
// are F16; K columns pre-scaled so weight = exp2(dot).
__device__ __forceinline__ void edge4_accum(
    uint4 ra, uint4 rb, uint4 rc, uint4 rd,
    bool mA, bool mB, bool mC, bool mD,
    h2 q01, h2 q23,
    float& z, float& u0, float& u1, float& u2, float& u3)
{
    float pa = dot2f(u_to_h2(ra.x), q01, 0.f); pa = dot2f(u_to_h2(ra.y), q23, pa);
    float pb = dot2f(u_to_h2(rb.x), q01, 0.f); pb = dot2f(u_to_h2(rb.y), q23, pb);
    float pc = dot2f(u_to_h2(rc.x), q01, 0.f); pc = dot2f(u_to_h2(rc.y), q23, pc);
    float pd = dot2f(u_to_h2(rd.x), q01, 0.f); pd = dot2f(u_to_h2(rd.y), q23, pd);
    pa = xor1_add(pa); pb = xor1_add(pb); pc = xor1_add(pc); pd = xor1_add(pd);
    pa = xor2_add(pa); pb = xor2_add(pb); pc = xor2_add(pc); pd = xor2_add(pd);
    pa = xor4_add(pa); pb = xor4_add(pb); pc = xor4_add(pc); pd = xor4_add(pd);
    float ea = EXP2F(pa); if (!mA) ea = 0.f;
    float eb = EXP2F(pb); if (!mB) eb = 0.f;
    float ec = EXP2F(pc); if (!mC) ec = 0.f;
    float ed = EXP2F(pd); if (!mD) ed = 0.f;
    z += (ea + eb) + (ec + ed);
    h2 va, vb;
    va = u_to_h2(ra.z); vb = u_to_h2(ra.w);
    u0 = fmaf(ea, (float)va.x, u0); u1 = fmaf(ea, (float)va.y, u1);
    u2 = fmaf(ea, (float)vb.x, u2); u3 = fmaf(ea, (float)vb.y, u3);
    va = u_to_h2(rb.z); vb = u_to_h2(rb.w);
    u0 = fmaf(eb, (float)va.x, u0); u1 = fmaf(eb, (float)va.y, u1);
    u2 = fmaf(eb, (float)vb.x, u2); u3 = fmaf(eb, (float)vb.y, u3);
    va = u_to_h2(rc.z); vb = u_to_h2(rc.w);
    u0 = fmaf(ec, (float)va.x, u0); u1 = fmaf(ec, (float)va.y, u1);
    u2 = fmaf(ec, (float)vb.x, u2); u3 = fmaf(ec, (float)vb.y, u3);
    va = u_to_h2(rd.z); vb = u_to_h2(rd.w);
    u0 = fmaf(ed, (float)va.x, u0); u1 = fmaf(ed, (float)va.y, u1);
    u2 = fmaf(ed, (float)vb.x, u2); u3 = fmaf(ed, (float)vb.y, u3);
}

__global__ __launch_bounds__(256) void aggregate_all(
    const ushort* __restrict__ Q0, const ushort* __restrict__ Q1,
    const ushort* __restrict__ KV0, const ushort* __restrict__ KV1,
    const ushort* __restrict__ KV2,
    const int* __restrict__ sorted, const int* __restrict__ counts,
    __hip_bfloat16* __restrict__ aggR0, __hip_bfloat16* __restrict__ aggR1,
    __hip_bfloat16* __restrict__ aggR2)
{
    int n = (blockIdx.x * 256 + threadIdx.x) >> 6;   // grid exact: 0..NN-1
    int lane = threadIdx.x & 63;
    int r = blockIdx.y;
    const ushort *Q, *KV; __hip_bfloat16* outp;
    if (r == 0)      { Q = Q1; KV = KV0; outp = aggR0; }
    else if (r == 1) { Q = Q0; KV = KV1; outp = aggR1; }
    else             { Q = Q1; KV = KV2; outp = aggR2; }
    int gw = r * NN + n;

    int hl = lane & 31;
    int half = lane >> 5;

    // ---- issue first batch + all address calc up front
    int cnt = min(counts[gw], CAP);
    uint2 qr = *(const uint2*)(Q + (size_t)n * 128 + hl * 4);
    const int* elist = sorted + (size_t)gw * CAP;
    int4 v0 = *(const int4*)elist;
    int4 v1 = *(const int4*)(elist + 4);
    int4 v2 = *(const int4*)(elist + 8);
    int4 v3 = *(const int4*)(elist + 12);

    int i0 = half ? v0.y : v0.x;
    int i1 = half ? v0.w : v0.z;
    int i2 = half ? v1.y : v1.x;
    int i3 = half ? v1.w : v1.z;
    int j0 = half ? v2.y : v2.x;
    int j1 = half ? v2.w : v2.z;
    int j2 = half ? v3.y : v3.x;
    int j3 = half ? v3.w : v3.z;
    uint4 ra = *(const uint4*)(KV + (size_t)(unsigned)(i0 * 256 + hl * 8));
    uint4 rb = *(const uint4*)(KV + (size_t)(unsigned)(i1 * 256 + hl * 8));
    uint4 rc = *(const uint4*)(KV + (size_t)(unsigned)(i2 * 256 + hl * 8));
    uint4 rd = *(const uint4*)(KV + (size_t)(unsigned)(i3 * 256 + hl * 8));

    h2 q01 = u_to_h2(qr.x), q23 = u_to_h2(qr.y);

    bool mA = (0 + half) < cnt, mB = (2 + half) < cnt, mC = (4 + half) < cnt, mD = (6 + half) < cnt;
    float u0 = 0.f, u1 = 0.f, u2 = 0.f, u3 = 0.f, z = 0.f;
    edge4_accum(ra, rb, rc, rd, mA, mB, mC, mD, q01, q23, z, u0, u1, u2, u3);

    if (cnt > 8) {   // uniform branch: 55% of waves skip the second gather batch entirely
        uint4 sa = *(const uint4*)(KV + (size_t)(unsigned)(j0 * 256 + hl * 8));
        uint4 sb = *(const uint4*)(KV + (size_t)(unsigned)(j1 * 256 + hl * 8));
        uint4 sc = *(const uint4*)(KV + (size_t)(unsigned)(j2 * 256 + hl * 8));
        uint4 sd = *(const uint4*)(KV + (size_t)(unsigned)(j3 * 256 + hl * 8));
        bool nA = (8 + half) < cnt, nB = (10 + half) < cnt, nC = (12 + half) < cnt, nD = (14 + half) < cnt;
        edge4_accum(sa, sb, sc, sd, nA, nB, nC, nD, q01, q23, z, u0, u1, u2, u3);

        for (int i = 16; i < cnt; i += 4) {   // rare tail (P(cnt>16) ~ 0.4%)
            int eA = i + half, eB = i + 2 + half;
            int sA = elist[min(eA, cnt - 1)];
            int sB = elist[min(eB, cnt - 1)];
            uint4 ta = *(const uint4*)(KV + (size_t)(unsigned)(sA * 256 + hl * 8));
            uint4 tb = *(const uint4*)(KV + (size_t)(unsigned)(sB * 256 + hl * 8));
            float pa = dot2f(u_to_h2(ta.x), q01, 0.f); pa = dot2f(u_to_h2(ta.y), q23, pa);
            float pb = dot2f(u_to_h2(tb.x), q01, 0.f); pb = dot2f(u_to_h2(tb.y), q23, pb);
            pa = xor1_add(pa); pb = xor1_add(pb);
            pa = xor2_add(pa); pb = xor2_add(pb);
            pa = xor4_add(pa); pb = xor4_add(pb);
            float ea = EXP2F(pa);
            float eb = EXP2F(pb);
            if (eA >= cnt) ea = 0.f;
            if (eB >= cnt) eb = 0.f;
            z += ea + eb;
            h2 va = u_to_h2(ta.z), vb = u_to_h2(ta.w);
            u0 = fmaf(ea, (float)va.x, u0); u1 = fmaf(ea, (float)va.y, u1);
            u2 = fmaf(ea, (float)vb.x, u2); u3 = fmaf(ea, (float)vb.y, u3);
            va = u_to_h2(tb.z); vb = u_to_h2(tb.w);
            u0 = fmaf(eb, (float)va.x, u0); u1 = fmaf(eb, (float)va.y, u1);
            u2 = fmaf(eb, (float)vb.x, u2); u3 = fmaf(eb, (float)vb.y, u3);
        }
    }

    z  += __shfl_xor(z, 32);
    u0 += __shfl_xor(u0, 32);
    u1 += __shfl_xor(u1, 32);
    u2 += __shfl_xor(u2, 32);
    u3 += __shfl_xor(u3, 32);
    if (half == 0) {
        float inv = (cnt > 0) ? 1.f / z : 0.f;
        __hip_bfloat162 o0 = __float22bfloat162_rn(make_float2(u0 * inv, u1 * inv));
        __hip_bfloat162 o1 = __float22bfloat162_rn(make_float2(u2 * inv, u3 * inv));
        union { uint2 u; __hip_bfloat162 h[2]; } pk2;
        pk2.h[0] = o0; pk2.h[1] = o1;
        *(uint2*)(outp + (size_t)n * 128 + hl * 4) = pk2.u;
    }
}

// ---------------------------------------------------------------- launch
extern "C" void kernel_launch(void* const* d_in, const int* in_sizes, int n_in,
                              void* d_out, int out_size, void* d_ws, size_t ws_size,
                              hipStream_t stream)
{
    const float* h0      = (const float*)d_in[0];
    const float* h1      = (const float*)d_in[1];
    const float* Wk      = (const float*)d_in[2];
    const float* bk      = (const float*)d_in[3];
    const float* Wq      = (const float*)d_in[4];
    const float* bq      = (const float*)d_in[5];
    const float* Wv      = (const float*)d_in[6];
    const float* bv      = (const float*)d_in[7];
    const float* Wa      = (const float*)d_in[8];
    const float* ba      = (const float*)d_in[9];
    const float* rel_att = (const float*)d_in[10];
    const float* rel_msg = (const float*)d_in[11];
    const float* rel_pri = (const float*)d_in[12];
    const float* skip    = (const float*)d_in[13];
    const int*   src0    = (const int*)d_in[14];
    const int*   dst0    = (const int*)d_in[15];
    const int*   src1    = (const int*)d_in[16];
    const int*   dst1    = (const int*)d_in[17];
    const int*   src2    = (const int*)d_in[18];
    const int*   dst2    = (const int*)d_in[19];
    float* out = (float*)d_out;

    char* w = (char*)d_ws;
    auto alloc = [&](size_t bytes) -> char* {
        char* p = w; w += (bytes + 255) & ~(size_t)255; return p;
    };
    __hip_bfloat16* Wcat0T = (__hip_bfloat16*)alloc(384 * 128 * 2);
    __hip_bfloat16* Wcat1T = (__hip_bfloat16*)alloc(640 * 128 * 2);
    __hip_bfloat16* WaT    = (__hip_bfloat16*)alloc(2 * 128 * 128 * 2);
    float* bcat0 = (float*)alloc(384 * sizeof(float));
    float* bcat1 = (float*)alloc(640 * sizeof(float));
    ushort* Q0  = (ushort*)alloc((size_t)NN * 128 * 2);
    ushort* Q1  = (ushort*)alloc((size_t)NN * 128 * 2);
    ushort* KV0 = (ushort*)alloc((size_t)NN * 256 * 2);
    ushort* KV1 = (ushort*)alloc((size_t)NN * 256 * 2);
    ushort* KV2 = (ushort*)alloc((size_t)NN * 256 * 2);
    __hip_bfloat16* aggR0 = (__hip_bfloat16*)alloc((size_t)NN * 128 * 2);
    __hip_bfloat16* aggR1 = (__hip_bfloat16*)alloc((size_t)NN * 128 * 2);
    __hip_bfloat16* aggR2 = (__hip_bfloat16*)alloc((size_t)NN * 128 * 2);
    int* cursor  = (int*)alloc(3 * NN * sizeof(int));
    int* sorted  = (int*)alloc((size_t)3 * NN * CAP * sizeof(int));

    // Guard: if ws too small, launch nothing -> clean absmax failure, not OOB abort.
    if ((size_t)(w - (char*)d_ws) > ws_size) return;

    // cursor and sorted are contiguous (modulo 256B pad): zeroed by prep's zero-blocks.
    size_t zlen = (size_t)((char*)sorted - (char*)cursor) + (size_t)3 * NN * CAP * sizeof(int);
    int zero_n4 = (int)(zlen / 16);                 // int4 count (zlen is 16B-multiple)
    int ZB = (zero_n4 + 1023) / 1024;               // 256 thr x 4 int4 each

    prep<<<FUSEB + ZB, 256, 0, stream>>>(
        Wk, bk, Wq, bq, Wv, bv, rel_att, rel_msg, rel_pri, Wa,
        Wcat0T, Wcat1T, WaT, bcat0, bcat1, cursor, zero_n4);

    const int ROWB = (NN + 127) / 128;  // 391
    proj_both<<<dim3(SCATX + ROWB, 2), 256, 0, stream>>>(
        h0, h1, Wcat0T, Wcat1T, bcat0, bcat1,
        Q0, Q1, KV0, KV1, KV2,
        src0, dst0, src1, dst1, src2, dst2, cursor, sorted);

    const int AG = (NN * 64) / 256;   // 12500 per relation (exact)
    aggregate_all<<<dim3(AG, 3), 256, 0, stream>>>(Q0, Q1, KV0, KV1, KV2, sorted, cursor,
                                                   aggR0, aggR1, aggR2);

    epi_both<<<dim3(ROWB, 2), 256, 0, stream>>>(aggR0, aggR1, aggR2, WaT, ba, out, skip, h0, h1);
}

// Round 6
// 309.535 us; speedup vs baseline: 1.1398x; 1.1398x over previous
//
#include <hip/hip_runtime.h>
#include <hip/hip_bf16.h>
#include <math.h>

// HGT layer forward, MI355X.
//  - fold rel_att/rel_msg einsums into projection weights; KV interleave baked into the
//    fused weight COLUMN ORDER (cols independent -> permutation is numerically identity)
//  - rel_pri * (1/sqrt(DK)) * log2(e) folded into the fused K columns (and k-bias) ->
//    aggregate applies exp2 directly to the dot product
//  - Q/KV intermediate planes stored as F16: score dot = v_dot2_f32_f16, message accum
//    fmaf (v_fma_mix) -> no unpack ops in the aggregate inner loop
//  - scatter REPLACED by atomic-free two-phase binning (R0/R3/R5 evidence: the global
//    atomic scatter is a ~85us coherence-point line-op wall, immune to ILP/occupancy):
//      phase A (in prep): bin edges by dst>>8 into fixed per-(block,bucket) slices,
//        LDS counters only, NO global atomics, no memset needed
//      phase B (in proj_both, overlaps GEMM): one block per bucket builds the full
//        256-row sorted image in LDS, streams it out fully coalesced (also replaces
//        the 24.6MB zero-fill). seg/cnt2 overlay aggR planes (disjoint lifetimes).
//  - aggregate: sorted rows zero-padded -> gather addresses depend only on elist; first
//    8-edge batch + all addr calc upfront; second batch gated by uniform cnt>8
//  - epi: fp32 LDS stage -> coalesced float4 Hres blend + store
//  - fixed-capacity buckets (CAP=40, deg~Poisson(8))

#define NN 50000
#define EE 400000
#define CAP 40
#define NBKT 196          // dst buckets per relation (width 256); also edge-chunks/relation
#define SLICE 40          // per-(block,bucket) slice capacity (mean 10.4, +11sigma safe)

typedef __bf16 bf16x8 __attribute__((ext_vector_type(8)));
typedef float floatx4 __attribute__((ext_vector_type(4)));
typedef _Float16 h2 __attribute__((ext_vector_type(2)));

#if __has_builtin(__builtin_amdgcn_exp2f)
#define EXP2F(x) __builtin_amdgcn_exp2f(x)
#else
#define EXP2F(x) exp2f(x)
#endif

__device__ __forceinline__ h2 u_to_h2(unsigned int u) {
    union { unsigned int u; h2 h; } x; x.u = u; return x.h;
}

__device__ __forceinline__ float dot2f(h2 a, h2 b, float c) {
#if __has_builtin(__builtin_amdgcn_fdot2)
    return __builtin_amdgcn_fdot2(a, b, c, false);
#else
    return fmaf((float)a.x, (float)b.x, fmaf((float)a.y, (float)b.y, c));
#endif
}

// xor-butterfly add stages; same pairwise tree as __shfl_xor version -> bit-identical.
__device__ __forceinline__ float xor1_add(float x) {
#if __has_builtin(__builtin_amdgcn_mov_dpp)
    int y = __builtin_amdgcn_mov_dpp(__float_as_int(x), 0xB1, 0xf, 0xf, true); // quad_perm [1,0,3,2]
    return x + __int_as_float(y);
#else
    return x + __shfl_xor(x, 1);
#endif
}
__device__ __forceinline__ float xor2_add(float x) {
#if __has_builtin(__builtin_amdgcn_mov_dpp)
    int y = __builtin_amdgcn_mov_dpp(__float_as_int(x), 0x4E, 0xf, 0xf, true); // quad_perm [2,3,0,1]
    return x + __int_as_float(y);
#else
    return x + __shfl_xor(x, 2);
#endif
}
__device__ __forceinline__ float xor4_add(float x) {
#if __has_builtin(__builtin_amdgcn_ds_swizzle)
    int y = __builtin_amdgcn_ds_swizzle(__float_as_int(x), 0x101F); // xor lane^4
    return x + __int_as_float(y);
#else
    return x + __shfl_xor(x, 4);
#endif
}

// ---------------------------------------------------------------- prep: fuse weights + phase A
// Fuse region (blocks [0,FUSEB)):
//   Wcat0T [384col][128k]: q0 | rel0-KV(256, interleaved col order)
//   Wcat1T [640col][128k]: q1 | rel1-KV(256) | rel2-KV(256)
//   K columns (and k-bias) pre-scaled by rel_pri[r][h]/sqrt(DK)*log2e. WaT [2][128][128].
// Phase A region (blocks [FUSEB, FUSEB+3*NBKT)): bin 2048 edges/block by dst>>8 into
//   seg[r][bucket][blk][SLICE] (packed (dst&255)<<16 | src), counts to cnt2[r][blk][bucket].
//   No global atomics; every cnt2 cell rewritten each launch -> no zeroing needed.
#define FUSEB 640
__global__ __launch_bounds__(256) void prep(
    const float* __restrict__ Wk, const float* __restrict__ bk,
    const float* __restrict__ Wq, const float* __restrict__ bq,
    const float* __restrict__ Wv, const float* __restrict__ bv,
    const float* __restrict__ rel_att, const float* __restrict__ rel_msg,
    const float* __restrict__ rel_pri, const float* __restrict__ Wa,
    __hip_bfloat16* __restrict__ Wcat0T, __hip_bfloat16* __restrict__ Wcat1T,
    __hip_bfloat16* __restrict__ WaT,
    float* __restrict__ bcat0, float* __restrict__ bcat1,
    const int* __restrict__ s0, const int* __restrict__ d0,
    const int* __restrict__ s1, const int* __restrict__ d1,
    const int* __restrict__ s2, const int* __restrict__ d2,
    int* __restrict__ seg, int* __restrict__ cnt2)
{
    __shared__ int cur[NBKT];
    if (blockIdx.x >= FUSEB) {
        // ---- phase A: bin edges into fixed slices (LDS counters only)
        int ab = blockIdx.x - FUSEB;        // [0, 3*NBKT)
        int r = ab / NBKT;
        int blk = ab - r * NBKT;
        const int* S = (r == 0) ? s0 : (r == 1) ? s1 : s2;
        const int* D = (r == 0) ? d0 : (r == 1) ? d1 : d2;
        for (int t = threadIdx.x; t < NBKT; t += 256) cur[t] = 0;
        __syncthreads();
        int* segr = seg + (size_t)r * NBKT * NBKT * SLICE;
        int e0 = blk * 2048 + threadIdx.x * 8;
        if (e0 + 8 <= EE) {
            int sv[8], dv[8];
            *(int4*)&sv[0] = *(const int4*)(S + e0);
            *(int4*)&sv[4] = *(const int4*)(S + e0 + 4);
            *(int4*)&dv[0] = *(const int4*)(D + e0);
            *(int4*)&dv[4] = *(const int4*)(D + e0 + 4);
            #pragma unroll
            for (int j = 0; j < 8; ++j) {
                int d = dv[j];
                int bkt = d >> 8;
                int pos = atomicAdd(&cur[bkt], 1);
                if (pos < SLICE)
                    segr[((size_t)bkt * NBKT + blk) * SLICE + pos] = sv[j] | ((d & 255) << 16);
            }
        } else {
            for (int j = 0; j < 8; ++j) {
                int e = e0 + j;
                if (e >= EE) break;
                int d = D[e];
                int bkt = d >> 8;
                int pos = atomicAdd(&cur[bkt], 1);
                if (pos < SLICE)
                    segr[((size_t)bkt * NBKT + blk) * SLICE + pos] = S[e] | ((d & 255) << 16);
            }
        }
        __syncthreads();
        for (int t = threadIdx.x; t < NBKT; t += 256)
            cnt2[((size_t)r * NBKT + blk) * NBKT + t] = min(cur[t], SLICE);
        return;
    }
    int idx = blockIdx.x * 256 + threadIdx.x;
    const int R1 = 128 * 384, R2 = 128 * 640, R3 = 2 * 128 * 128;
    if (idx >= R1 + R2 + R3) return;
    if (idx >= R1 + R2) {               // WaT transpose region
        int t = idx - R1 - R2;
        int tt = t >> 14, rem = t & 16383;
        int k = rem >> 7, col = rem & 127;
        WaT[tt * 16384 + col * 128 + k] = __float2bfloat16(Wa[tt * 16384 + k * 128 + col]);
        return;
    }
    int typ, i, col;
    __hip_bfloat16* Wout; float* bout;
    if (idx < R1) { typ = 0; i = idx / 384; col = idx % 384; Wout = Wcat0T; bout = bcat0; }
    else { idx -= R1; typ = 1; i = idx / 640; col = idx % 640; Wout = Wcat1T; bout = bcat1; }
    float w, b;
    if (col < 128) {
        w = Wq[(typ * 128 + i) * 128 + col];
        b = bq[typ * 128 + col];
    } else {
        int kvcol = col - 128;
        int r = (typ == 0) ? 0 : (1 + (kvcol >> 8));
        int gc = kvcol & 255;
        int isV = (gc >> 2) & 1;
        int c = (gc >> 3) * 4 + (gc & 3);   // head-dim within 128
        int s = typ;
        const float* Wsrc = isV ? Wv : Wk;
        const float* bsrc = isV ? bv : bk;
        const float* rel  = isV ? rel_msg : rel_att;
        int h = c >> 5, j = c & 31;
        float acc = 0.f, bacc = 0.f;
        #pragma unroll
        for (int cc = 0; cc < 32; ++cc) {
            float rr = rel[((r * 4 + h) * 32 + cc) * 32 + j];
            acc  += Wsrc[(s * 128 + i) * 128 + h * 32 + cc] * rr;
            bacc += bsrc[s * 128 + h * 32 + cc] * rr;
        }
        if (!isV) {
            float sc = rel_pri[r * 4 + h] * (0.17677669529663687f * 1.4426950408889634f);
            acc *= sc; bacc *= sc;
        }
        w = acc; b = bacc;
    }
    Wout[col * 128 + i] = __float2bfloat16(w);   // transposed [col][k]
    if (i == 0) bout[col] = b;
}

// ---------------------------------------------------------------- projection GEMM + phase B
// Blocks x < SCATX: phase B — one block per (relation, bucket): gather the bucket's
//   slices (coalesced), place into a full 256-row x CAP LDS image via LDS atomics,
//   stream the image + counts out fully coalesced (also provides the zero padding).
// Blocks x >= SCATX: GEMM. Stage A once; loop col-tiles. ct=0 -> Q[N][128]; else
//   KV_rel[N][256] slice. C-write: acc -> Bs -> coalesced dwordx4 stores. F16 outputs.
#define SCATX 294      // phase-B blocks per y-slice (2*294 = 3*NBKT)
__global__ __launch_bounds__(256) void proj_both(
    const float* __restrict__ h0, const float* __restrict__ h1,
    const __hip_bfloat16* __restrict__ W0T, const __hip_bfloat16* __restrict__ W1T,
    const float* __restrict__ b0, const float* __restrict__ b1,
    ushort* __restrict__ Q0, ushort* __restrict__ Q1,
    ushort* __restrict__ KV0, ushort* __restrict__ KV1,
    ushort* __restrict__ KV2,
    const int* __restrict__ seg, const int* __restrict__ cnt2,
    int* __restrict__ sorted_src, int* __restrict__ counts)
{
    __shared__ __align__(16) char smem[2 * 128 * 136 * 2];   // 69632 B, shared by both roles
    const int tid = threadIdx.x;

    if (blockIdx.x < SCATX) {
        // ---- phase B: bucket placement, fully in LDS, coalesced output
        int pb = blockIdx.y * SCATX + blockIdx.x;   // [0, 3*NBKT)
        int r = pb / NBKT;
        int b = pb - r * NBKT;
        int* stage  = (int*)smem;          // [256*CAP] = 40960 B
        int* cntl   = stage + 256 * CAP;   // [NBKT]
        int* rowcnt = cntl + NBKT;         // [256]
        if (tid < NBKT) cntl[tid] = cnt2[((size_t)r * NBKT + tid) * NBKT + b];
        rowcnt[tid] = 0;
        int4 z4 = make_int4(0, 0, 0, 0);
        #pragma unroll
        for (int it = 0; it < (256 * CAP) / 4 / 256; ++it)   // 10 int4 each
            ((int4*)stage)[it * 256 + tid] = z4;
        __syncthreads();

        const int* segb = seg + (size_t)(r * NBKT + b) * (NBKT * SLICE);
        const int NE4 = (NBKT * SLICE) / 4;                  // 1960
        for (int li4 = tid; li4 < NE4; li4 += 256) {
            int4 pv = ((const int4*)segb)[li4];
            int pvals[4] = { pv.x, pv.y, pv.z, pv.w };
            #pragma unroll
            for (int j = 0; j < 4; ++j) {
                int e = li4 * 4 + j;
                int s = e / SLICE;
                int k = e - s * SLICE;
                if (k < cntl[s]) {
                    int p = pvals[j];
                    int dlow = (unsigned)p >> 16;
                    int srcv = p & 0xFFFF;
                    int pos = atomicAdd(&rowcnt[dlow], 1);
                    if (pos < CAP) stage[dlow * CAP + pos] = srcv;
                }
            }
        }
        __syncthreads();

        int nrows = min(256, NN - b * 256);
        int* gout = sorted_src + ((size_t)r * NN + b * 256) * CAP;
        int n4 = nrows * (CAP / 4);
        for (int li = tid; li < n4; li += 256)
            ((int4*)gout)[li] = ((int4*)stage)[li];
        if (tid < nrows) counts[(size_t)r * NN + b * 256 + tid] = rowcnt[tid];
        return;
    }

    typedef __hip_bfloat16 bfrow[136];
    typedef ushort usrow[136];
    bfrow* As = (bfrow*)smem;
    usrow* Bs = (usrow*)(smem + 128 * 136 * 2);

    const int row0 = (blockIdx.x - SCATX) * 128;
    const int typ = blockIdx.y;
    const float* A = typ ? h1 : h0;
    const __hip_bfloat16* WT = typ ? W1T : W0T;
    const float* bias = typ ? b1 : b0;
    const int ntiles = typ ? 5 : 3;

    #pragma unroll
    for (int it = 0; it < 16; ++it) {
        int li = it * 256 + tid;
        int r = li >> 5, k4 = (li & 31) * 4;
        int grow = row0 + r;
        float4 a4 = make_float4(0.f, 0.f, 0.f, 0.f);
        if (grow < NN) a4 = *(const float4*)(A + (size_t)grow * 128 + k4);
        As[r][k4 + 0] = __float2bfloat16(a4.x);
        As[r][k4 + 1] = __float2bfloat16(a4.y);
        As[r][k4 + 2] = __float2bfloat16(a4.z);
        As[r][k4 + 3] = __float2bfloat16(a4.w);
    }

    const int lane = tid & 63;
    const int wv = tid >> 6;
    const int wr = (wv & 1) * 64, wc = (wv >> 1) * 64;
    const int lr = lane & 15, kq = lane >> 4;

    for (int ct = 0; ct < ntiles; ++ct) {
        __syncthreads();
        #pragma unroll
        for (int it = 0; it < 8; ++it) {
            int li = it * 256 + tid;
            int c = li >> 4, k8 = (li & 15) * 8;
            *(uint4*)&Bs[c][k8] = *(const uint4*)(WT + (size_t)(ct * 128 + c) * 128 + k8);
        }
        __syncthreads();

        floatx4 acc[4][4];
        #pragma unroll
        for (int i = 0; i < 4; ++i)
            #pragma unroll
            for (int j = 0; j < 4; ++j)
                acc[i][j] = (floatx4){0.f, 0.f, 0.f, 0.f};

        #pragma unroll
        for (int kc = 0; kc < 128; kc += 32) {
            bf16x8 a[4], b[4];
            #pragma unroll
            for (int i = 0; i < 4; ++i) a[i] = *(const bf16x8*)&As[wr + i * 16 + lr][kc + kq * 8];
            #pragma unroll
            for (int j = 0; j < 4; ++j) b[j] = *(const bf16x8*)&Bs[wc + j * 16 + lr][kc + kq * 8];
            #pragma unroll
            for (int i = 0; i < 4; ++i)
                #pragma unroll
                for (int j = 0; j < 4; ++j)
                    acc[i][j] = __builtin_amdgcn_mfma_f32_16x16x32_bf16(a[i], b[j], acc[i][j], 0, 0, 0);
        }

        float biasv[4];
        #pragma unroll
        for (int j = 0; j < 4; ++j) biasv[j] = bias[ct * 128 + wc + j * 16 + lr];

        __syncthreads();
        #pragma unroll
        for (int i = 0; i < 4; ++i)
            #pragma unroll
            for (int reg = 0; reg < 4; ++reg) {
                int row = wr + i * 16 + kq * 4 + reg;
                #pragma unroll
                for (int j = 0; j < 4; ++j) {
                    union { _Float16 h; ushort s; } cv;
                    cv.h = (_Float16)(acc[i][j][reg] + biasv[j]);
                    Bs[row][wc + j * 16 + lr] = cv.s;
                }
            }
        __syncthreads();

        ushort* plane; int ld, toff;
        if (ct == 0) { plane = typ ? Q1 : Q0; ld = 128; toff = 0; }
        else {
            int rel = typ ? (1 + ((ct - 1) >> 1)) : 0;
            plane = (rel == 0) ? KV0 : (rel == 1) ? KV1 : KV2;
            ld = 256; toff = ((ct - 1) & 1) * 128;
        }
        #pragma unroll
        for (int it = 0; it < 8; ++it) {
            int li = it * 256 + tid;
            int row = li >> 4, chunk = (li & 15) * 8;
            int grow = row0 + row;
            if (grow < NN)
                *(uint4*)(plane + (size_t)grow * ld + toff + chunk) = *(const uint4*)&Bs[row][chunk];
        }
    }
}

// ---------------------------------------------------------------- epilogue GEMM
__device__ __forceinline__ void epi_body(
    char* smem,
    const __hip_bfloat16* __restrict__ A0, const __hip_bfloat16* __restrict__ A1, float ascale,
    const __hip_bfloat16* __restrict__ BT, const float* __restrict__ bias,
    float* __restrict__ C, const float* __restrict__ skipGate, const float* __restrict__ Hres)
{
    typedef __hip_bfloat16 bfrow[136];
    bfrow* As = (bfrow*)smem;
    bfrow* Bs = (bfrow*)(smem + 128 * 136 * 2);
    typedef float frow[132];
    frow* St = (frow*)smem;                 // overlays As+Bs after MFMA
    const int tid = threadIdx.x;
    const int row0 = blockIdx.x * 128;

    #pragma unroll
    for (int it = 0; it < 8; ++it) {
        int li = it * 256 + tid;
        int c = li >> 4, k8 = (li & 15) * 8;
        *(uint4*)&Bs[c][k8] = *(const uint4*)(BT + (size_t)c * 128 + k8);
    }
    #pragma unroll
    for (int it = 0; it < 8; ++it) {
        int li = it * 256 + tid;
        int r = li >> 4, k8 = (li & 15) * 8;
        int grow = row0 + r;
        __hip_bfloat162 o2[4];
        if (grow < NN) {
            const __hip_bfloat162* pa = (const __hip_bfloat162*)(A0 + (size_t)grow * 128 + k8);
            if (A1) {
                const __hip_bfloat162* pb = (const __hip_bfloat162*)(A1 + (size_t)grow * 128 + k8);
                #pragma unroll
                for (int u = 0; u < 4; ++u) {
                    float2 fa = __bfloat1622float2(pa[u]);
                    float2 fb = __bfloat1622float2(pb[u]);
                    fa.x = (fa.x + fb.x) * ascale;
                    fa.y = (fa.y + fb.y) * ascale;
                    o2[u] = __float22bfloat162_rn(fa);
                }
            } else {
                #pragma unroll
                for (int u = 0; u < 4; ++u) o2[u] = pa[u];
            }
        } else {
            __hip_bfloat162 zz = __float22bfloat162_rn(make_float2(0.f, 0.f));
            #pragma unroll
            for (int u = 0; u < 4; ++u) o2[u] = zz;
        }
        __hip_bfloat162* dst = (__hip_bfloat162*)&As[r][k8];
        #pragma unroll
        for (int u = 0; u < 4; ++u) dst[u] = o2[u];
    }
    __syncthreads();

    const int lane = tid & 63;
    const int wv = tid >> 6;
    const int wr = (wv & 1) * 64, wc = (wv >> 1) * 64;
    const int lr = lane & 15, kq = lane >> 4;

    floatx4 acc[4][4];
    #pragma unroll
    for (int i = 0; i < 4; ++i)
        #pragma unroll
        for (int j = 0; j < 4; ++j)
            acc[i][j] = (floatx4){0.f, 0.f, 0.f, 0.f};

    #pragma unroll
    for (int kc = 0; kc < 128; kc += 32) {
        bf16x8 a[4], b[4];
        #pragma unroll
        for (int i = 0; i < 4; ++i) a[i] = *(const bf16x8*)&As[wr + i * 16 + lr][kc + kq * 8];
        #pragma unroll
        for (int j = 0; j < 4; ++j) b[j] = *(const bf16x8*)&Bs[wc + j * 16 + lr][kc + kq * 8];
        #pragma unroll
        for (int i = 0; i < 4; ++i)
            #pragma unroll
            for (int j = 0; j < 4; ++j)
                acc[i][j] = __builtin_amdgcn_mfma_f32_16x16x32_bf16(a[i], b[j], acc[i][j], 0, 0, 0);
    }

    float sg = *skipGate;
    float alpha = 1.f / (1.f + expf(-sg));
    float beta = 1.f - alpha;
    float biasv[4];
    #pragma unroll
    for (int j = 0; j < 4; ++j) biasv[j] = bias[wc + j * 16 + lr];

    __syncthreads();
    #pragma unroll
    for (int i = 0; i < 4; ++i)
        #pragma unroll
        for (int reg = 0; reg < 4; ++reg) {
            int row = wr + i * 16 + kq * 4 + reg;
            #pragma unroll
            for (int j = 0; j < 4; ++j)
                St[row][wc + j * 16 + lr] = acc[i][j][reg] + biasv[j];
        }
    __syncthreads();

    #pragma unroll
    for (int it = 0; it < 16; ++it) {
        int li = it * 256 + tid;
        int row = li >> 5, chunk = (li & 31) * 4;
        int grow = row0 + row;
        if (grow < NN) {
            float4 v = *(const float4*)&St[row][chunk];
            float4 hr = *(const float4*)(Hres + (size_t)grow * 128 + chunk);
            v.x = v.x * alpha + hr.x * beta;
            v.y = v.y * alpha + hr.y * beta;
            v.z = v.z * alpha + hr.z * beta;
            v.w = v.w * alpha + hr.w * beta;
            *(float4*)(C + (size_t)grow * 128 + chunk) = v;
        }
    }
}

__global__ __launch_bounds__(256) void epi_both(
    const __hip_bfloat16* __restrict__ aggR0, const __hip_bfloat16* __restrict__ aggR1,
    const __hip_bfloat16* __restrict__ aggR2,
    const __hip_bfloat16* __restrict__ WaT, const float* __restrict__ ba,
    float* __restrict__ out, const float* __restrict__ skip,
    const float* __restrict__ h0, const float* __restrict__ h1)
{
    __shared__ __align__(16) char smem[128 * 136 * 2 * 2];
    if (blockIdx.y == 0)
        epi_body(smem, aggR1, nullptr, 1.f, WaT, ba, out, skip, h0);
    else
        epi_body(smem, aggR0, aggR2, 0.5f, WaT + 16384, ba + 128,
                 out + (size_t)NN * 128, skip + 1, h1);
}

// ---------------------------------------------------------------- aggregate
// Grid y = relation; one wave per dst node. hl=lane&31 covers dims 4hl..4hl+3;
// half=lane>>5 is edge parity. sorted rows zero-padded by phase B -> gather
// addresses depend only on elist; masks (cnt) consumed at exp stage only.
// First 8-edge batch + all address calc upfront; second batch loads gated by
// uniform cnt>8. KV/Q planes are F16; K columns pre-scaled so weight = exp2(dot).
__device__ __forceinline__ void edge4_accum(
    uint4 ra, uint4 rb, uint4 rc, uint4 rd,
    bool mA, bool mB, bool mC, bool mD,
    h2 q01, h2 q23,
    float& z, float& u0, float& u1, float& u2, float& u3)
{
    float pa = dot2f(u_to_h2(ra.x), q01, 0.f); pa = dot2f(u_to_h2(ra.y), q23, pa);
    float pb = dot2f(u_to_h2(rb.x), q01, 0.f); pb = dot2f(u_to_h2(rb.y), q23, pb);
    float pc = dot2f(u_to_h2(rc.x), q01, 0.f); pc = dot2f(u_to_h2(rc.y), q23, pc);
    float pd = dot2f(u_to_h2(rd.x), q01, 0.f); pd = dot2f(u_to_h2(rd.y), q23, pd);
    pa = xor1_add(pa); pb = xor1_add(pb); pc = xor1_add(pc); pd = xor1_add(pd);
    pa = xor2_add(pa); pb = xor2_add(pb); pc = xor2_add(pc); pd = xor2_add(pd);
    pa = xor4_add(pa); pb = xor4_add(pb); pc = xor4_add(pc); pd = xor4_add(pd);
    float ea = EXP2F(pa); if (!mA) ea = 0.f;
    float eb = EXP2F(pb); if (!mB) eb = 0.f;
    float ec = EXP2F(pc); if (!mC) ec = 0.f;
    float ed = EXP2F(pd); if (!mD) ed = 0.f;
    z += (ea + eb) + (ec + ed);
    h2 va, vb;
    va = u_to_h2(ra.z); vb = u_to_h2(ra.w);
    u0 = fmaf(ea, (float)va.x, u0); u1 = fmaf(ea, (float)va.y, u1);
    u2 = fmaf(ea, (float)vb.x, u2); u3 = fmaf(ea, (float)vb.y, u3);
    va = u_to_h2(rb.z); vb = u_to_h2(rb.w);
    u0 = fmaf(eb, (float)va.x, u0); u1 = fmaf(eb, (float)va.y, u1);
    u2 = fmaf(eb, (float)vb.x, u2); u3 = fmaf(eb, (float)vb.y, u3);
    va = u_to_h2(rc.z); vb = u_to_h2(rc.w);
    u0 = fmaf(ec, (float)va.x, u0); u1 = fmaf(ec, (float)va.y, u1);
    u2 = fmaf(ec, (float)vb.x, u2); u3 = fmaf(ec, (float)vb.y, u3);
    va = u_to_h2(rd.z); vb = u_to_h2(rd.w);
    u0 = fmaf(ed, (float)va.x, u0); u1 = fmaf(ed, (float)va.y, u1);
    u2 = fmaf(ed, (float)vb.x, u2); u3 = fmaf(ed, (float)vb.y, u3);
}

__global__ __launch_bounds__(256) void aggregate_all(
    const ushort* __restrict__ Q0, const ushort* __restrict__ Q1,
    const ushort* __restrict__ KV0, const ushort* __restrict__ KV1,
    const ushort* __restrict__ KV2,
    const int* __restrict__ sorted, const int* __restrict__ counts,
    __hip_bfloat16* __restrict__ aggR0, __hip_bfloat16* __restrict__ aggR1,
    __hip_bfloat16* __restrict__ aggR2)
{
    int n = (blockIdx.x * 256 + threadIdx.x) >> 6;   // grid exact: 0..NN-1
    int lane = threadIdx.x & 63;
    int r = blockIdx.y;
    const ushort *Q, *KV; __hip_bfloat16* outp;
    if (r == 0)      { Q = Q1; KV = KV0; outp = aggR0; }
    else if (r == 1) { Q = Q0; KV = KV1; outp = aggR1; }
    else             { Q = Q1; KV = KV2; outp = aggR2; }
    int gw = r * NN + n;

    int hl = lane & 31;
    int half = lane >> 5;

    // ---- issue first batch + all address calc up front
    int cnt = min(counts[gw], CAP);
    uint2 qr = *(const uint2*)(Q + (size_t)n * 128 + hl * 4);
    const int* elist = sorted + (size_t)gw * CAP;
    int4 v0 = *(const int4*)elist;
    int4 v1 = *(const int4*)(elist + 4);
    int4 v2 = *(const int4*)(elist + 8);
    int4 v3 = *(const int4*)(elist + 12);

    int i0 = half ? v0.y : v0.x;
    int i1 = half ? v0.w : v0.z;
    int i2 = half ? v1.y : v1.x;
    int i3 = half ? v1.w : v1.z;
    int j0 = half ? v2.y : v2.x;
    int j1 = half ? v2.w : v2.z;
    int j2 = half ? v3.y : v3.x;
    int j3 = half ? v3.w : v3.z;
    uint4 ra = *(const uint4*)(KV + (size_t)(unsigned)(i0 * 256 + hl * 8));
    uint4 rb = *(const uint4*)(KV + (size_t)(unsigned)(i1 * 256 + hl * 8));
    uint4 rc = *(const uint4*)(KV + (size_t)(unsigned)(i2 * 256 + hl * 8));
    uint4 rd = *(const uint4*)(KV + (size_t)(unsigned)(i3 * 256 + hl * 8));

    h2 q01 = u_to_h2(qr.x), q23 = u_to_h2(qr.y);

    bool mA = (0 + half) < cnt, mB = (2 + half) < cnt, mC = (4 + half) < cnt, mD = (6 + half) < cnt;
    float u0 = 0.f, u1 = 0.f, u2 = 0.f, u3 = 0.f, z = 0.f;
    edge4_accum(ra, rb, rc, rd, mA, mB, mC, mD, q01, q23, z, u0, u1, u2, u3);

    if (cnt > 8) {   // uniform branch: ~55% of waves skip the second gather batch
        uint4 sa = *(const uint4*)(KV + (size_t)(unsigned)(j0 * 256 + hl * 8));
        uint4 sb = *(const uint4*)(KV + (size_t)(unsigned)(j1 * 256 + hl * 8));
        uint4 sc = *(const uint4*)(KV + (size_t)(unsigned)(j2 * 256 + hl * 8));
        uint4 sd = *(const uint4*)(KV + (size_t)(unsigned)(j3 * 256 + hl * 8));
        bool nA = (8 + half) < cnt, nB = (10 + half) < cnt, nC = (12 + half) < cnt, nD = (14 + half) < cnt;
        edge4_accum(sa, sb, sc, sd, nA, nB, nC, nD, q01, q23, z, u0, u1, u2, u3);

        for (int i = 16; i < cnt; i += 4) {   // rare tail (P(cnt>16) ~ 0.4%)
            int eA = i + half, eB = i + 2 + half;
            int sA = elist[min(eA, cnt - 1)];
            int sB = elist[min(eB, cnt - 1)];
            uint4 ta = *(const uint4*)(KV + (size_t)(unsigned)(sA * 256 + hl * 8));
            uint4 tb = *(const uint4*)(KV + (size_t)(unsigned)(sB * 256 + hl * 8));
            float pa = dot2f(u_to_h2(ta.x), q01, 0.f); pa = dot2f(u_to_h2(ta.y), q23, pa);
            float pb = dot2f(u_to_h2(tb.x), q01, 0.f); pb = dot2f(u_to_h2(tb.y), q23, pb);
            pa = xor1_add(pa); pb = xor1_add(pb);
            pa = xor2_add(pa); pb = xor2_add(pb);
            pa = xor4_add(pa); pb = xor4_add(pb);
            float ea = EXP2F(pa);
            float eb = EXP2F(pb);
            if (eA >= cnt) ea = 0.f;
            if (eB >= cnt) eb = 0.f;
            z += ea + eb;
            h2 va = u_to_h2(ta.z), vb = u_to_h2(ta.w);
            u0 = fmaf(ea, (float)va.x, u0); u1 = fmaf(ea, (float)va.y, u1);
            u2 = fmaf(ea, (float)vb.x, u2); u3 = fmaf(ea, (float)vb.y, u3);
            va = u_to_h2(tb.z); vb = u_to_h2(tb.w);
            u0 = fmaf(eb, (float)va.x, u0); u1 = fmaf(eb, (float)va.y, u1);
            u2 = fmaf(eb, (float)vb.x, u2); u3 = fmaf(eb, (float)vb.y, u3);
        }
    }

    z  += __shfl_xor(z, 32);
    u0 += __shfl_xor(u0, 32);
    u1 += __shfl_xor(u1, 32);
    u2 += __shfl_xor(u2, 32);
    u3 += __shfl_xor(u3, 32);
    if (half == 0) {
        float inv = (cnt > 0) ? 1.f / z : 0.f;
        __hip_bfloat162 o0 = __float22bfloat162_rn(make_float2(u0 * inv, u1 * inv));
        __hip_bfloat162 o1 = __float22bfloat162_rn(make_float2(u2 * inv, u3 * inv));
        union { uint2 u; __hip_bfloat162 h[2]; } pk2;
        pk2.h[0] = o0; pk2.h[1] = o1;
        *(uint2*)(outp + (size_t)n * 128 + hl * 4) = pk2.u;
    }
}

// ---------------------------------------------------------------- launch
extern "C" void kernel_launch(void* const* d_in, const int* in_sizes, int n_in,
                              void* d_out, int out_size, void* d_ws, size_t ws_size,
                              hipStream_t stream)
{
    const float* h0      = (const float*)d_in[0];
    const float* h1      = (const float*)d_in[1];
    const float* Wk      = (const float*)d_in[2];
    const float* bk      = (const float*)d_in[3];
    const float* Wq      = (const float*)d_in[4];
    const float* bq      = (const float*)d_in[5];
    const float* Wv      = (const float*)d_in[6];
    const float* bv      = (const float*)d_in[7];
    const float* Wa      = (const float*)d_in[8];
    const float* ba      = (const float*)d_in[9];
    const float* rel_att = (const float*)d_in[10];
    const float* rel_msg = (const float*)d_in[11];
    const float* rel_pri = (const float*)d_in[12];
    const float* skip    = (const float*)d_in[13];
    const int*   src0    = (const int*)d_in[14];
    const int*   dst0    = (const int*)d_in[15];
    const int*   src1    = (const int*)d_in[16];
    const int*   dst1    = (const int*)d_in[17];
    const int*   src2    = (const int*)d_in[18];
    const int*   dst2    = (const int*)d_in[19];
    float* out = (float*)d_out;

    char* w = (char*)d_ws;
    auto alloc = [&](size_t bytes) -> char* {
        char* p = w; w += (bytes + 255) & ~(size_t)255; return p;
    };
    __hip_bfloat16* Wcat0T = (__hip_bfloat16*)alloc(384 * 128 * 2);
    __hip_bfloat16* Wcat1T = (__hip_bfloat16*)alloc(640 * 128 * 2);
    __hip_bfloat16* WaT    = (__hip_bfloat16*)alloc(2 * 128 * 128 * 2);
    float* bcat0 = (float*)alloc(384 * sizeof(float));
    float* bcat1 = (float*)alloc(640 * sizeof(float));
    ushort* Q0  = (ushort*)alloc((size_t)NN * 128 * 2);
    ushort* Q1  = (ushort*)alloc((size_t)NN * 128 * 2);
    ushort* KV0 = (ushort*)alloc((size_t)NN * 256 * 2);
    ushort* KV1 = (ushort*)alloc((size_t)NN * 256 * 2);
    ushort* KV2 = (ushort*)alloc((size_t)NN * 256 * 2);
    __hip_bfloat16* aggR0 = (__hip_bfloat16*)alloc((size_t)NN * 128 * 2);
    __hip_bfloat16* aggR1 = (__hip_bfloat16*)alloc((size_t)NN * 128 * 2);
    __hip_bfloat16* aggR2 = (__hip_bfloat16*)alloc((size_t)NN * 128 * 2);
    int* counts  = (int*)alloc(3 * NN * sizeof(int));
    int* sorted  = (int*)alloc((size_t)3 * NN * CAP * sizeof(int));

    // seg/cnt2 overlay the aggR planes: phase A/B (prep, proj_both) use them and finish
    // before aggregate writes aggR. aggR0..2 are contiguous (each 12.8MB, 256-aligned).
    // seg: 3*196*196*40 ints = 18.44 MB; cnt2: 3*196*196 ints = 0.46 MB; total < 38.4 MB.
    int* seg  = (int*)aggR0;
    int* cnt2 = seg + (size_t)3 * NBKT * NBKT * SLICE;

    // Guard: if ws too small, launch nothing -> clean absmax failure, not OOB abort.
    if ((size_t)(w - (char*)d_ws) > ws_size) return;

    prep<<<FUSEB + 3 * NBKT, 256, 0, stream>>>(
        Wk, bk, Wq, bq, Wv, bv, rel_att, rel_msg, rel_pri, Wa,
        Wcat0T, Wcat1T, WaT, bcat0, bcat1,
        src0, dst0, src1, dst1, src2, dst2, seg, cnt2);

    const int ROWB = (NN + 127) / 128;  // 391
    proj_both<<<dim3(SCATX + ROWB, 2), 256, 0, stream>>>(
        h0, h1, Wcat0T, Wcat1T, bcat0, bcat1,
        Q0, Q1, KV0, KV1, KV2,
        seg, cnt2, sorted, counts);

    const int AG = (NN * 64) / 256;   // 12500 per relation (exact)
    aggregate_all<<<dim3(AG, 3), 256, 0, stream>>>(Q0, Q1, KV0, KV1, KV2, sorted, counts,
                                                   aggR0, aggR1, aggR2);

    epi_both<<<dim3(ROWB, 2), 256, 0, stream>>>(aggR0, aggR1, aggR2, WaT, ba, out, skip, h0, h1);
}